// Round 14
// baseline (5844.690 us; speedup 1.0000x reference)
//
#include <hip/hip_runtime.h>

#define HH 512
#define BB 16
#define TT 256
#define VV 32
#define TPB 512
#define NBLK 256
#define PITCH 516   // LDS row pitch (floats)

#define BAR_INTS 512   // 256 global slots + 256 per-group slots

typedef unsigned long long ull;

struct KArgs {
  const float* enc; const float* h0in; const float* c0in;
  const float* Wq; const float* bq; const float* vatt; const float* vb;
  const float* Wih0; const float* bih0; const float* Whh0; const float* bhh0;
  const float* Wih1; const float* bih1; const float* Whh1; const float* bhh1;
  const float* Wout; const float* bout;
  const float* Kproj; ull* H0tag; float* H1buf; ull* qWtag; float* Ug; float* Zg;
  int* bar; float* out;
};

struct Smem {
  float W0e[4][2][PITCH];   // Wih0[g*512+j][0:512]    (enc_t part)
  float W0c[4][2][PITCH];   // Wih0[g*512+j][512:1024] (ctx part)
  float W0h[4][2][PITCH];   // Whh0
  float W1x[4][2][PITCH];   // Wih1
  float W1h[4][2][PITCH];   // Whh1
  float Wqr[2][PITCH];
  float Wor[2][PITCH];
  float vv[HH];
  union { float qrow[HH]; float red[8][64]; } qr;  // time-disjoint: qrow=phase B, red=dots
  float stg[BB][PITCH];     // staging: h1 -> enc -> U -> h0n
  float pre0[BB][4][2];     // bs0 + W0h*h0_prev (B4win of t-1) + W0e*enc (A of t)
  float pre1[BB][4][2];     // bs1 + W1h*h1_prev (A of t)
  float cst[2][2][BB];      // c state [layer][jj][b]
  float scw[16];            // attention exp-weights
  float zinv[BB];
  float bs0[4][2];
  float bs1[4][2];
  float bqv[2], boutv[2];
};

__device__ __forceinline__ float fsig(float x){ return 1.0f/(1.0f + __expf(-x)); }
__device__ __forceinline__ float ftanh(float x){
  float ee = __expf(2.0f*x);
  return 1.0f - 2.0f/(ee + 1.0f);
}

// relaxed agent-scope (cross-XCD coherent, write-through, no wb/inv) — proven transport
__device__ __forceinline__ void stcc(float* p, float v){
  __hip_atomic_store(p, v, __ATOMIC_RELAXED, __HIP_MEMORY_SCOPE_AGENT);
}
__device__ __forceinline__ float ldcc(const float* p){
  return __hip_atomic_load(p, __ATOMIC_RELAXED, __HIP_MEMORY_SCOPE_AGENT);
}
__device__ __forceinline__ float2 ld2cc(const float* p){
  ull v = __hip_atomic_load((const ull*)p, __ATOMIC_RELAXED, __HIP_MEMORY_SCOPE_AGENT);
  union { ull u; float2 f; } c; c.u = v;
  return c.f;
}

// (value, tag) pair in one atomic 8B word — atomicity carries the ordering
__device__ __forceinline__ ull  ppack(float v, int tag){
  return (ull)(unsigned)__float_as_int(v) | ((ull)(unsigned)tag << 32);
}
__device__ __forceinline__ float pval(ull x){ return __int_as_float((int)(unsigned)x); }
__device__ __forceinline__ int   ptag(ull x){ return (int)(unsigned)(x >> 32); }
__device__ __forceinline__ void st_pair(ull* p, float v, int tag){
  __hip_atomic_store(p, ppack(v, tag), __ATOMIC_RELAXED, __HIP_MEMORY_SCOPE_AGENT);
}
__device__ __forceinline__ ull ld_pair(const ull* p){
  return __hip_atomic_load(p, __ATOMIC_RELAXED, __HIP_MEMORY_SCOPE_AGENT);
}

// contiguous coherent load of a 16x512 float buffer + LDS stage (8 pairs/thread)
__device__ __forceinline__ void ldbuf_cc(const float* __restrict__ src,
                                         float2* __restrict__ v, int tid){
  #pragma unroll
  for (int it = 0; it < 8; ++it)
    v[it] = ld2cc(&src[(it*TPB + tid)*2]);
}
__device__ __forceinline__ void stg_regs(const float2* __restrict__ v,
                                         float (* __restrict__ stg)[PITCH], int tid){
  #pragma unroll
  for (int it = 0; it < 8; ++it){
    const int i2 = (it*TPB + tid)*2;
    *(float2*)&stg[i2 >> 9][i2 & 511] = v[it];
  }
}

// poll-stage a tagged 16x512 buffer (16 pairs/thread, exact tag match)
__device__ __forceinline__ void poll_stage16(const ull* __restrict__ r, int exptag,
                                             float (* __restrict__ stg)[PITCH], int tid){
  int spins = 0;
  for (;;){
    int ok = 1;
    #pragma unroll
    for (int it = 0; it < 16; ++it){
      const int idx = it*TPB + tid;
      const ull v = ld_pair(&r[idx]);
      ok &= (ptag(v) == exptag);
      stg[idx >> 9][idx & 511] = pval(v);
    }
    if (ok) break;
    __builtin_amdgcn_s_sleep(1);
    if (++spins > (1 << 20)) break;   // safety valve: wrong answer beats a hang
  }
}

// ---- global split barrier (r8/r10/r12/r13-proven) ----
__device__ __forceinline__ void gbar_arrive(int* __restrict__ bar, int e, int bid){
  __syncthreads();   // per-wave vmcnt drain -> all coherent stores/atomics landed
  if (threadIdx.x == 0)
    __hip_atomic_store(&bar[bid], e, __ATOMIC_RELAXED, __HIP_MEMORY_SCOPE_AGENT);
}
__device__ __forceinline__ void gbar_wait(int* __restrict__ bar, int e, int bid){
  if (threadIdx.x < 64){
    const ull* p = (const ull*)bar;   // 128 ulls
    const int i0 = threadIdx.x * 2;
    int spins = 0;
    for (;;){
      ull v0 = __hip_atomic_load(&p[i0],     __ATOMIC_RELAXED, __HIP_MEMORY_SCOPE_AGENT);
      ull v1 = __hip_atomic_load(&p[i0 + 1], __ATOMIC_RELAXED, __HIP_MEMORY_SCOPE_AGENT);
      const int a0 = (int)v0, a1 = (int)(v0 >> 32), a2 = (int)v1, a3 = (int)(v1 >> 32);
      const int ok = (a0 >= e) & (a1 >= e) & (a2 >= e) & (a3 >= e);
      if (__all(ok)) break;
      __builtin_amdgcn_s_sleep(1);
      if (++spins > (1 << 20)) break;   // safety valve
    }
  }
  __syncthreads();
}

// ---- per-group (16-block) barrier (r12/r13-proven) ----
__device__ __forceinline__ void gbar2(int* __restrict__ bar2, int et, int bid, int ba){
  __syncthreads();   // drains this block's U/Z atomics
  if (threadIdx.x == 0)
    __hip_atomic_store(&bar2[bid], et, __ATOMIC_RELAXED, __HIP_MEMORY_SCOPE_AGENT);
  if (threadIdx.x < 64){
    const ull* p = (const ull*)bar2 + ba*8;  // 16 ints
    int spins = 0;
    for (;;){
      int ok = 1;
      if (threadIdx.x < 8){
        ull v = __hip_atomic_load(&p[threadIdx.x], __ATOMIC_RELAXED, __HIP_MEMORY_SCOPE_AGENT);
        ok = ((int)v >= et) & ((int)(v >> 32) >= et);
      }
      if (__all(ok)) break;
      __builtin_amdgcn_s_sleep(1);
      if (++spins > (1 << 20)) break;   // safety valve
    }
  }
  __syncthreads();
}

// 8-wave dot: wave w -> (jj = w>>2, 128-h segment = w&3); lane = (g<<4)|b
__device__ __forceinline__ void dot8(const float* __restrict__ W,
                                     const float (* __restrict__ stg)[PITCH],
                                     float (* __restrict__ red)[64],
                                     int wave, int lane){
  const int jj = wave >> 2, off = (wave & 3) << 7;
  const int b = lane & 15, g = lane >> 4;
  const float* wrow = W + (size_t)(g*2 + jj)*PITCH + off;
  const float* xrow = &stg[b][off];
  float a0 = 0.f, a1 = 0.f, a2 = 0.f, a3 = 0.f;
  #pragma unroll
  for (int h = 0; h < 128; h += 16){
    const float4 w0 = *(const float4*)&wrow[h];      const float4 x0 = *(const float4*)&xrow[h];
    const float4 w1 = *(const float4*)&wrow[h + 4];  const float4 x1 = *(const float4*)&xrow[h + 4];
    const float4 w2 = *(const float4*)&wrow[h + 8];  const float4 x2 = *(const float4*)&xrow[h + 8];
    const float4 w3 = *(const float4*)&wrow[h + 12]; const float4 x3 = *(const float4*)&xrow[h + 12];
    a0 = fmaf(w0.x,x0.x, fmaf(w0.y,x0.y, fmaf(w0.z,x0.z, fmaf(w0.w,x0.w, a0))));
    a1 = fmaf(w1.x,x1.x, fmaf(w1.y,x1.y, fmaf(w1.z,x1.z, fmaf(w1.w,x1.w, a1))));
    a2 = fmaf(w2.x,x2.x, fmaf(w2.y,x2.y, fmaf(w2.z,x2.z, fmaf(w2.w,x2.w, a2))));
    a3 = fmaf(w3.x,x3.x, fmaf(w3.y,x3.y, fmaf(w3.z,x3.z, fmaf(w3.w,x3.w, a3))));
  }
  red[wave][lane] = (a0 + a1) + (a2 + a3);
}

__global__ void init_kernel(const float* __restrict__ h0in, ull* __restrict__ H0tag,
                            float* __restrict__ H1buf, ull* __restrict__ qWtag,
                            float* __restrict__ Ug, float* __restrict__ Zg,
                            int* __restrict__ bar){
  const int i = blockIdx.x*blockDim.x + threadIdx.x;
  if (i < BB*HH){
    H0tag[i] = ppack(h0in[i], 0);        // tag 0: never matches any poll (t+1 >= 1)
    H1buf[i] = h0in[BB*HH + i];          // layer 1 initial (parity slot 0)
    qWtag[i] = ppack(0.f, 0);
  }
  if (i < 2*BB*HH) Ug[i] = 0.0f;
  if (i < 32) Zg[i] = 0.0f;
  if (i < BAR_INTS) bar[i] = 0;
}

// Kproj = enc @ Wk^T + bk
__global__ __launch_bounds__(256, 1) void kproj_kernel(const float* __restrict__ enc,
                                                       const float* __restrict__ Wk,
                                                       const float* __restrict__ bk,
                                                       float* __restrict__ Kproj){
  __shared__ float er[BB][PITCH];
  const int bid = blockIdx.x, tid = threadIdx.x;
  const int wave = tid >> 6, lane = tid & 63;
  const int r = lane & 15, q = lane >> 4;
  const int row0 = bid*16;
  #pragma unroll
  for (int it = 0; it < 8; ++it){
    const int idx = (it*256 + tid)*4;
    const int rr = idx >> 9, h = idx & 511;
    *(float4*)&er[rr][h] = *(const float4*)&enc[(size_t)(row0+rr)*HH + h];
  }
  __syncthreads();
  float4 xr[32];
  #pragma unroll
  for (int i = 0; i < 32; ++i) xr[i] = *(const float4*)&er[r][q*128 + i*4];
  for (int k = 0; k < 128; ++k){
    const int hk = wave*128 + k;
    const float* wrow = Wk + (size_t)hk*HH + q*128;
    float acc = 0.f;
    #pragma unroll
    for (int i = 0; i < 32; ++i){
      const float4 w4 = *(const float4*)&wrow[i*4];
      acc = fmaf(w4.x,xr[i].x, fmaf(w4.y,xr[i].y, fmaf(w4.z,xr[i].z, fmaf(w4.w,xr[i].w, acc))));
    }
    acc += __shfl_xor(acc, 16);
    acc += __shfl_xor(acc, 32);
    if (lane < 16) Kproj[(size_t)(row0 + r)*HH + hk] = acc + bk[hk];
  }
}

__global__ __launch_bounds__(TPB, 1) void decoder_persist(KArgs a){
  __shared__ Smem S;
  const int bid = blockIdx.x, tid = threadIdx.x;
  const int wave = tid >> 6, lane = tid & 63;
  const int lb = lane & 15, lg = lane >> 4;
  const int j0 = bid*2;
  const int ba = bid >> 4, tb = (bid & 15) * 16;   // attention assignment
  int* bar2 = a.bar + 256;

  // ---- one-time: weights to LDS ----
  for (int g = 0; g < 4; ++g){
    for (int jj = 0; jj < 2; ++jj){
      const int row = g*HH + j0 + jj;
      for (int h = tid; h < HH; h += TPB){
        S.W0e[g][jj][h] = a.Wih0[(size_t)row*(2*HH) + h];
        S.W0c[g][jj][h] = a.Wih0[(size_t)row*(2*HH) + HH + h];
        S.W0h[g][jj][h] = a.Whh0[(size_t)row*HH + h];
        S.W1x[g][jj][h] = a.Wih1[(size_t)row*HH + h];
        S.W1h[g][jj][h] = a.Whh1[(size_t)row*HH + h];
      }
    }
  }
  for (int jj = 0; jj < 2; ++jj){
    const int d = bid*2 + jj, vo = d & 31;
    for (int h = tid; h < HH; h += TPB){
      S.Wqr[jj][h] = a.Wq[(size_t)(j0+jj)*HH + h];
      S.Wor[jj][h] = a.Wout[(size_t)vo*HH + h];
    }
  }
  for (int h = tid; h < HH; h += TPB) S.vv[h] = a.vatt[h];
  if (tid < 16){
    S.cst[0][0][tid] = a.c0in[0*BB*HH + tid*HH + j0];
    S.cst[0][1][tid] = a.c0in[0*BB*HH + tid*HH + j0 + 1];
    S.cst[1][0][tid] = a.c0in[1*BB*HH + tid*HH + j0];
    S.cst[1][1][tid] = a.c0in[1*BB*HH + tid*HH + j0 + 1];
  }
  if (tid < 8){
    const int g = tid & 3, jj = tid >> 2;
    const int row = g*HH + j0 + jj;
    S.bs0[g][jj] = a.bih0[row] + a.bhh0[row];
    S.bs1[g][jj] = a.bih1[row] + a.bhh1[row];
  }
  if (tid < 2){
    S.bqv[tid] = a.bq[j0 + tid];
    S.boutv[tid] = a.bout[(bid*2 + tid) & 31];
  }
  const float vb0 = a.vb[0];

  // ---- step-invariant attention operands -> registers ----
  float r_kp[2][8];
  #pragma unroll
  for (int i = 0; i < 2; ++i){
    const float* kp = a.Kproj + (size_t)(ba*TT + tb + wave*2 + i)*HH;
    #pragma unroll
    for (int k = 0; k < 8; ++k) r_kp[i][k] = kp[lane + 64*k];
  }
  float r_e[16];
  #pragma unroll
  for (int lt = 0; lt < 16; ++lt)
    r_e[lt] = a.enc[(size_t)(ba*TT + tb + lt)*HH + tid];
  float4 r_en[4];
  #pragma unroll
  for (int it = 0; it < 4; ++it){
    const int idx = (it*TPB + tid)*4;
    r_en[it] = *(const float4*)&a.enc[(size_t)((idx >> 9)*TT + 0)*HH + (idx & 511)];
  }
  __syncthreads();

  // ---- prologue: pre0 = bs0 + W0h @ h0_init ----
  {
    #pragma unroll
    for (int it = 0; it < 4; ++it){
      const int idx = (it*TPB + tid)*4;
      *(float4*)&S.stg[idx >> 9][idx & 511] = *(const float4*)&a.h0in[idx];
    }
    __syncthreads();
    dot8(&S.W0h[0][0][0], S.stg, S.qr.red, wave, lane);
    __syncthreads();
    if (tid < 128){
      const int jj = tid >> 6, l = tid & 63, g = l >> 4, b = l & 15;
      S.pre0[b][g][jj] = (S.qr.red[jj*4+0][l] + S.qr.red[jj*4+1][l])
                       + (S.qr.red[jj*4+2][l] + S.qr.red[jj*4+3][l]) + S.bs0[g][jj];
    }
    __syncthreads();
  }

  int e = 0;
  for (int t = 0; t < TT; ++t){
    const int par = t & 1, parn = par ^ 1;

    // ========== Phase A: h1 load+stage, logits(t-1), qW -> tagged store ==========
    float2 r_h1[8];
    ldbuf_cc(a.H1buf + par*(BB*HH), r_h1, tid);
    stg_regs(r_h1, S.stg, tid);
    __syncthreads();   // h1 staged

    if (wave < 2){
      if (t > 0){   // logits for step t-1 from staged h1
        const int d = bid*2 + wave, bo = d >> 5, vo = d & 31;
        float acc = 0.f;
        #pragma unroll
        for (int k = 0; k < 8; ++k){
          const int h = lane + 64*k;
          acc = fmaf(S.Wor[wave][h], S.stg[bo][h], acc);
        }
        #pragma unroll
        for (int off = 32; off; off >>= 1) acc += __shfl_xor(acc, off);
        if (lane == 0) a.out[(size_t)(bo*TT + (t-1))*VV + vo] = acc + S.boutv[wave];
      }
    } else if (wave < 4){  // qW = h1 @ Wq^T + bq (2-accumulator chains)
      const int jj = wave - 2;
      const int off0 = lg * 128;
      float a0 = 0.f, a1 = 0.f;
      #pragma unroll
      for (int h = 0; h < 128; h += 8){
        const float4 w0 = *(const float4*)&S.Wqr[jj][off0 + h];
        const float4 x0 = *(const float4*)&S.stg[lb][off0 + h];
        const float4 w1 = *(const float4*)&S.Wqr[jj][off0 + h + 4];
        const float4 x1 = *(const float4*)&S.stg[lb][off0 + h + 4];
        a0 = fmaf(w0.x,x0.x, fmaf(w0.y,x0.y, fmaf(w0.z,x0.z, fmaf(w0.w,x0.w, a0))));
        a1 = fmaf(w1.x,x1.x, fmaf(w1.y,x1.y, fmaf(w1.z,x1.z, fmaf(w1.w,x1.w, a1))));
      }
      float acc = a0 + a1;
      acc += __shfl_xor(acc, 16);
      acc += __shfl_xor(acc, 32);
      if (lane < 16)
        st_pair(&a.qWtag[lane*HH + j0 + jj], acc + S.bqv[jj], t + 1);  // publish, tag t+1
    }

    // A work (fills the publish->visible gap): W1h dot + pre1; enc stage + W0e dot
    dot8(&S.W1h[0][0][0], S.stg, S.qr.red, wave, lane);   // h1 @ Whh1^T
    __syncthreads();
    if (tid < 128){
      const int jj = tid >> 6, l = tid & 63, g = l >> 4, b = l & 15;
      S.pre1[b][g][jj] = (S.qr.red[jj*4+0][l] + S.qr.red[jj*4+1][l])
                       + (S.qr.red[jj*4+2][l] + S.qr.red[jj*4+3][l]) + S.bs1[g][jj];
    }
    #pragma unroll
    for (int it = 0; it < 4; ++it){               // enc_t stage
      const int idx = (it*TPB + tid)*4;
      *(float4*)&S.stg[idx >> 9][idx & 511] = r_en[it];
    }
    __syncthreads();   // enc staged, pre1 done
    dot8(&S.W0e[0][0][0], S.stg, S.qr.red, wave, lane);   // enc_t part of Wih0
    __syncthreads();
    if (tid < 128){
      const int jj = tid >> 6, l = tid & 63, g = l >> 4, b = l & 15;
      S.pre0[b][g][jj] += (S.qr.red[jj*4+0][l] + S.qr.red[jj*4+1][l])
                        + (S.qr.red[jj*4+2][l] + S.qr.red[jj*4+3][l]);
    }
    __syncthreads();   // red reads done -> qrow (alias) safe to write

    // ========== Phase B: attention (poll qW pairs, tag t+1 — B1 deleted) ==========
    {
      float* Up = a.Ug + par*(BB*HH);
      float* Zp = a.Zg + par*16;
      {
        const ull* q = a.qWtag + ba*HH;
        int spins = 0;
        for (;;){
          const ull v = ld_pair(&q[tid]);
          if (ptag(v) == t + 1){ S.qr.qrow[tid] = pval(v); break; }
          __builtin_amdgcn_s_sleep(1);
          if (++spins > (1 << 20)) break;   // safety valve
        }
      }
      __syncthreads();
      #pragma unroll
      for (int i = 0; i < 2; ++i){
        float acc = 0.f;
        #pragma unroll
        for (int k = 0; k < 8; ++k){
          const int h = lane + 64*k;
          acc = fmaf(S.vv[h], ftanh(S.qr.qrow[h] + r_kp[i][k]), acc);
        }
        #pragma unroll
        for (int off = 32; off; off >>= 1) acc += __shfl_xor(acc, off);
        if (lane == 0) S.scw[wave*2 + i] = __expf(acc + vb0);  // |score|<=~18, exp safe
      }
      __syncthreads();
      float u = 0.f;
      #pragma unroll
      for (int lt = 0; lt < 16; ++lt)
        u = fmaf(S.scw[lt], r_e[lt], u);
      unsafeAtomicAdd(&Up[ba*HH + tid], u);
      if (tid == 0){
        float zs = 0.f;
        #pragma unroll
        for (int lt = 0; lt < 16; ++lt) zs += S.scw[lt];
        unsafeAtomicAdd(&Zp[ba], zs);
      }
    }
    gbar2(bar2, t + 1, bid, ba);   // ---- B2 per-GROUP: group ba's U,Z complete ----

    // ========== Phase C: LSTM0 -> h0n tagged publish (B3 deleted) ==========
    {
      float2 r_u[8];
      ldbuf_cc(a.Ug + par*(BB*HH), r_u, tid);
      if (tid < 16) S.zinv[tid] = 1.0f / ldcc(&a.Zg[par*16 + tid]);
      stg_regs(r_u, S.stg, tid);
      __syncthreads();
      dot8(&S.W0c[0][0][0], S.stg, S.qr.red, wave, lane);  // raw-U part of Wih0
      __syncthreads();
      if (tid < 32){
        const int b = tid & 15, jj = tid >> 4;
        const float zi = S.zinv[b];
        float gv[4];
        #pragma unroll
        for (int g = 0; g < 4; ++g){
          const int l = g*16 + b;
          gv[g] = S.pre0[b][g][jj]
                + ((S.qr.red[jj*4+0][l] + S.qr.red[jj*4+1][l])
                 + (S.qr.red[jj*4+2][l] + S.qr.red[jj*4+3][l])) * zi;
        }
        const float cold = S.cst[0][jj][b];
        const float ii = fsig(gv[0]), ff = fsig(gv[1]);
        const float gg = ftanh(gv[2]), oo = fsig(gv[3]);
        const float cn = ff*cold + ii*gg;
        S.cst[0][jj][b] = cn;
        st_pair(&a.H0tag[b*HH + j0 + jj], oo * ftanh(cn), t + 1);  // publish, tag t+1
      }
    }

    // prefetch next step's enc_t while h0n publications land (read-only)
    {
      const int tn = (t + 1 < TT) ? (t + 1) : t;
      #pragma unroll
      for (int it = 0; it < 4; ++it){
        const int idx = (it*TPB + tid)*4;
        r_en[it] = *(const float4*)&a.enc[(size_t)((idx >> 9)*TT + tn)*HH + (idx & 511)];
      }
    }

    // ========== Phase D: poll h0n (tag t+1), LSTM1, B4 global ==========
    {
      // zero next step's U/Z buffers (drained by B4-arrive; adders act after B4-wait)
      if (tid < 32) stcc(&a.Ug[parn*(BB*HH) + bid*32 + tid], 0.0f);
      if (bid == 0 && tid < 16) stcc(&a.Zg[parn*16 + tid], 0.0f);

      poll_stage16(a.H0tag, t + 1, S.stg, tid);
      __syncthreads();   // h0n staged
      dot8(&S.W1x[0][0][0], S.stg, S.qr.red, wave, lane);  // h0n @ Wih1^T
      __syncthreads();
      if (tid < 32){
        const int b = tid & 15, jj = tid >> 4;
        float gv[4];
        #pragma unroll
        for (int g = 0; g < 4; ++g){
          const int l = g*16 + b;
          gv[g] = S.pre1[b][g][jj]
                + (S.qr.red[jj*4+0][l] + S.qr.red[jj*4+1][l])
                + (S.qr.red[jj*4+2][l] + S.qr.red[jj*4+3][l]);
        }
        const float cold = S.cst[1][jj][b];
        const float ii = fsig(gv[0]), ff = fsig(gv[1]);
        const float gg = ftanh(gv[2]), oo = fsig(gv[3]);
        const float cn = ff*cold + ii*gg;
        S.cst[1][jj][b] = cn;
        stcc(&a.H1buf[parn*(BB*HH) + b*HH + j0 + jj], oo * ftanh(cn));
      }
    }
    e++; gbar_arrive(a.bar, e, bid);   // ---- B4 ARRIVE (h1n stores drained) ----
    {
      // B4 window: W0h @ h0n -> pre0 for step t+1 (stg still holds h0n; red free)
      dot8(&S.W0h[0][0][0], S.stg, S.qr.red, wave, lane);
      __syncthreads();
      if (tid < 128){
        const int jj = tid >> 6, l = tid & 63, g = l >> 4, b = l & 15;
        S.pre0[b][g][jj] = (S.qr.red[jj*4+0][l] + S.qr.red[jj*4+1][l])
                         + (S.qr.red[jj*4+2][l] + S.qr.red[jj*4+3][l]) + S.bs0[g][jj];
      }
    }
    gbar_wait(a.bar, e, bid);          // ---- B4 WAIT: h1n visible -> next step ----
  }

  // tail: logits for t=255 (final h1 is in H1buf[0] since (255+1)&1==0)
  {
    float2 r_x[8];
    ldbuf_cc(a.H1buf, r_x, tid);
    stg_regs(r_x, S.stg, tid);
    __syncthreads();
    if (wave < 2){
      const int d = bid*2 + wave, bo = d >> 5, vo = d & 31;
      float acc = 0.f;
      #pragma unroll
      for (int k = 0; k < 8; ++k){
        const int h = lane + 64*k;
        acc = fmaf(S.Wor[wave][h], S.stg[bo][h], acc);
      }
      #pragma unroll
      for (int off = 32; off; off >>= 1) acc += __shfl_xor(acc, off);
      if (lane == 0) a.out[(size_t)(bo*TT + 255)*VV + vo] = acc + S.boutv[wave];
    }
  }
}

extern "C" void kernel_launch(void* const* d_in, const int* in_sizes, int n_in,
                              void* d_out, int out_size, void* d_ws, size_t ws_size,
                              hipStream_t stream){
  const float* enc  = (const float*)d_in[0];
  const float* h0in = (const float*)d_in[1];
  const float* c0in = (const float*)d_in[2];
  // d_in[3] audio_lengths: unused by the reference
  const float* Wq   = (const float*)d_in[4];
  const float* bq   = (const float*)d_in[5];
  const float* Wk   = (const float*)d_in[6];
  const float* bk   = (const float*)d_in[7];
  const float* vatt = (const float*)d_in[8];
  const float* vb   = (const float*)d_in[9];
  const float* Wih0 = (const float*)d_in[10];
  const float* bih0 = (const float*)d_in[11];
  const float* Whh0 = (const float*)d_in[12];
  const float* bhh0 = (const float*)d_in[13];
  const float* Wih1 = (const float*)d_in[14];
  const float* bih1 = (const float*)d_in[15];
  const float* Whh1 = (const float*)d_in[16];
  const float* bhh1 = (const float*)d_in[17];
  const float* Wout = (const float*)d_in[18];
  const float* bout = (const float*)d_in[19];

  float* ws    = (float*)d_ws;
  float* Kproj = ws;                                // B*T*H = 2097152 floats
  ull*   H0tag = (ull*)(Kproj + (size_t)BB*TT*HH);  // BB*HH pairs (16384 floats)
  float* H1buf = (float*)(H0tag + BB*HH);           // 2*B*H floats (parity)
  ull*   qWtag = (ull*)(H1buf + 2*BB*HH);           // BB*HH pairs (16384 floats)
  float* Ug    = (float*)(qWtag + BB*HH);           // 2*B*H (parity double-buffer)
  float* Zg    = Ug + 2*BB*HH;                      // 2*16
  int*   bar   = (int*)(Zg + 32);                   // BAR_INTS ints

  hipLaunchKernelGGL(init_kernel, dim3(64), dim3(256), 0, stream,
                     h0in, H0tag, H1buf, qWtag, Ug, Zg, bar);
  hipLaunchKernelGGL(kproj_kernel, dim3(256), dim3(256), 0, stream, enc, Wk, bk, Kproj);

  KArgs ka;
  ka.enc = enc; ka.h0in = h0in; ka.c0in = c0in;
  ka.Wq = Wq; ka.bq = bq; ka.vatt = vatt; ka.vb = vb;
  ka.Wih0 = Wih0; ka.bih0 = bih0; ka.Whh0 = Whh0; ka.bhh0 = bhh0;
  ka.Wih1 = Wih1; ka.bih1 = bih1; ka.Whh1 = Whh1; ka.bhh1 = bhh1;
  ka.Wout = Wout; ka.bout = bout;
  ka.Kproj = Kproj; ka.H0tag = H0tag; ka.H1buf = H1buf; ka.qWtag = qWtag;
  ka.Ug = Ug; ka.Zg = Zg; ka.bar = bar; ka.out = (float*)d_out;

  void* params[] = { (void*)&ka };
  hipLaunchCooperativeKernel((const void*)decoder_persist, dim3(NBLK), dim3(TPB),
                             params, 0, stream);
}

// Round 15
// 4769.514 us; speedup vs baseline: 1.2254x; 1.2254x over previous
//
#include <hip/hip_runtime.h>

#define HH 512
#define BB 16
#define TT 256
#define VV 32
#define TPB 512
#define NBLK 256
#define PITCH 516   // LDS row pitch (floats)

#define BAR_INTS 512   // 256 global slots + 256 per-group slots

typedef unsigned long long ull;

struct KArgs {
  const float* enc; const float* h0in; const float* c0in;
  const float* Wq; const float* bq; const float* vatt; const float* vb;
  const float* Wih0; const float* bih0; const float* Whh0; const float* bhh0;
  const float* Wih1; const float* bih1; const float* Whh1; const float* bhh1;
  const float* Wout; const float* bout;
  const float* Kproj; float* H0buf; float* H1buf; ull* qWtag; float* Ug; float* Zg;
  int* bar; float* out;
};

struct Smem {
  float W0e[4][2][PITCH];   // Wih0[g*512+j][0:512]    (enc_t part)
  float W0c[4][2][PITCH];   // Wih0[g*512+j][512:1024] (ctx part)
  float W0h[4][2][PITCH];   // Whh0
  float W1x[4][2][PITCH];   // Wih1
  float W1h[4][2][PITCH];   // Whh1
  float Wqr[2][PITCH];
  float Wor[2][PITCH];
  float vv[HH];
  union { float qrow[HH]; float red[8][64]; } qr;  // time-disjoint: qrow=phase B, red=dots
  float stg[BB][PITCH];     // staging: h1 -> enc -> U -> h0n
  float pre0[BB][4][2];     // bs0 + W0h*h0_prev (B4win of t-1) + W0e*enc (A of t)
  float pre1[BB][4][2];     // bs1 + W1h*h1_prev (A of t)
  float cst[2][2][BB];      // c state [layer][jj][b]
  float scw[16];            // attention exp-weights
  float zinv[BB];
  float bs0[4][2];
  float bs1[4][2];
  float bqv[2], boutv[2];
};

__device__ __forceinline__ float fsig(float x){ return 1.0f/(1.0f + __expf(-x)); }
__device__ __forceinline__ float ftanh(float x){
  float ee = __expf(2.0f*x);
  return 1.0f - 2.0f/(ee + 1.0f);
}

// relaxed agent-scope (cross-XCD coherent, write-through, no wb/inv) — proven transport
__device__ __forceinline__ void stcc(float* p, float v){
  __hip_atomic_store(p, v, __ATOMIC_RELAXED, __HIP_MEMORY_SCOPE_AGENT);
}
__device__ __forceinline__ float ldcc(const float* p){
  return __hip_atomic_load(p, __ATOMIC_RELAXED, __HIP_MEMORY_SCOPE_AGENT);
}
__device__ __forceinline__ float2 ld2cc(const float* p){
  ull v = __hip_atomic_load((const ull*)p, __ATOMIC_RELAXED, __HIP_MEMORY_SCOPE_AGENT);
  union { ull u; float2 f; } c; c.u = v;
  return c.f;
}

// (value, tag) pair in one atomic 8B word (r14-proven mechanism)
__device__ __forceinline__ ull  ppack(float v, int tag){
  return (ull)(unsigned)__float_as_int(v) | ((ull)(unsigned)tag << 32);
}
__device__ __forceinline__ float pval(ull x){ return __int_as_float((int)(unsigned)x); }
__device__ __forceinline__ int   ptag(ull x){ return (int)(unsigned)(x >> 32); }
__device__ __forceinline__ void st_pair(ull* p, float v, int tag){
  __hip_atomic_store(p, ppack(v, tag), __ATOMIC_RELAXED, __HIP_MEMORY_SCOPE_AGENT);
}
__device__ __forceinline__ ull ld_pair(const ull* p){
  return __hip_atomic_load(p, __ATOMIC_RELAXED, __HIP_MEMORY_SCOPE_AGENT);
}

// contiguous coherent load of a 16x512 buffer + LDS stage (8 pairs/thread)
__device__ __forceinline__ void ldbuf_cc(const float* __restrict__ src,
                                         float2* __restrict__ v, int tid){
  #pragma unroll
  for (int it = 0; it < 8; ++it)
    v[it] = ld2cc(&src[(it*TPB + tid)*2]);
}
__device__ __forceinline__ void stg_regs(const float2* __restrict__ v,
                                         float (* __restrict__ stg)[PITCH], int tid){
  #pragma unroll
  for (int it = 0; it < 8; ++it){
    const int i2 = (it*TPB + tid)*2;
    *(float2*)&stg[i2 >> 9][i2 & 511] = v[it];
  }
}

// ---- global split barrier (r8/r10/r12/r13-proven) ----
__device__ __forceinline__ void gbar_arrive(int* __restrict__ bar, int e, int bid){
  __syncthreads();   // per-wave vmcnt drain -> all coherent stores/atomics landed
  if (threadIdx.x == 0)
    __hip_atomic_store(&bar[bid], e, __ATOMIC_RELAXED, __HIP_MEMORY_SCOPE_AGENT);
}
__device__ __forceinline__ void gbar_wait(int* __restrict__ bar, int e, int bid){
  if (threadIdx.x < 64){
    const ull* p = (const ull*)bar;   // 128 ulls
    const int i0 = threadIdx.x * 2;
    int spins = 0;
    for (;;){
      ull v0 = __hip_atomic_load(&p[i0],     __ATOMIC_RELAXED, __HIP_MEMORY_SCOPE_AGENT);
      ull v1 = __hip_atomic_load(&p[i0 + 1], __ATOMIC_RELAXED, __HIP_MEMORY_SCOPE_AGENT);
      const int a0 = (int)v0, a1 = (int)(v0 >> 32), a2 = (int)v1, a3 = (int)(v1 >> 32);
      const int ok = (a0 >= e) & (a1 >= e) & (a2 >= e) & (a3 >= e);
      if (__all(ok)) break;
      __builtin_amdgcn_s_sleep(2);
      if (++spins > (1 << 20)) break;   // safety valve
    }
  }
  __syncthreads();
}

// ---- per-group (16-block) barrier (r12/r13-proven) ----
__device__ __forceinline__ void gbar2(int* __restrict__ bar2, int et, int bid, int ba){
  __syncthreads();   // drains this block's U/Z atomics
  if (threadIdx.x == 0)
    __hip_atomic_store(&bar2[bid], et, __ATOMIC_RELAXED, __HIP_MEMORY_SCOPE_AGENT);
  if (threadIdx.x < 64){
    const ull* p = (const ull*)bar2 + ba*8;  // 16 ints
    int spins = 0;
    for (;;){
      int ok = 1;
      if (threadIdx.x < 8){
        ull v = __hip_atomic_load(&p[threadIdx.x], __ATOMIC_RELAXED, __HIP_MEMORY_SCOPE_AGENT);
        ok = ((int)v >= et) & ((int)(v >> 32) >= et);
      }
      if (__all(ok)) break;
      __builtin_amdgcn_s_sleep(1);
      if (++spins > (1 << 20)) break;   // safety valve
    }
  }
  __syncthreads();
}

// 8-wave dot: wave w -> (jj = w>>2, 128-h segment = w&3); lane = (g<<4)|b
__device__ __forceinline__ void dot8(const float* __restrict__ W,
                                     const float (* __restrict__ stg)[PITCH],
                                     float (* __restrict__ red)[64],
                                     int wave, int lane){
  const int jj = wave >> 2, off = (wave & 3) << 7;
  const int b = lane & 15, g = lane >> 4;
  const float* wrow = W + (size_t)(g*2 + jj)*PITCH + off;
  const float* xrow = &stg[b][off];
  float a0 = 0.f, a1 = 0.f, a2 = 0.f, a3 = 0.f;
  #pragma unroll
  for (int h = 0; h < 128; h += 16){
    const float4 w0 = *(const float4*)&wrow[h];      const float4 x0 = *(const float4*)&xrow[h];
    const float4 w1 = *(const float4*)&wrow[h + 4];  const float4 x1 = *(const float4*)&xrow[h + 4];
    const float4 w2 = *(const float4*)&wrow[h + 8];  const float4 x2 = *(const float4*)&xrow[h + 8];
    const float4 w3 = *(const float4*)&wrow[h + 12]; const float4 x3 = *(const float4*)&xrow[h + 12];
    a0 = fmaf(w0.x,x0.x, fmaf(w0.y,x0.y, fmaf(w0.z,x0.z, fmaf(w0.w,x0.w, a0))));
    a1 = fmaf(w1.x,x1.x, fmaf(w1.y,x1.y, fmaf(w1.z,x1.z, fmaf(w1.w,x1.w, a1))));
    a2 = fmaf(w2.x,x2.x, fmaf(w2.y,x2.y, fmaf(w2.z,x2.z, fmaf(w2.w,x2.w, a2))));
    a3 = fmaf(w3.x,x3.x, fmaf(w3.y,x3.y, fmaf(w3.z,x3.z, fmaf(w3.w,x3.w, a3))));
  }
  red[wave][lane] = (a0 + a1) + (a2 + a3);
}

__global__ void init_kernel(const float* __restrict__ h0in, float* __restrict__ H0buf,
                            float* __restrict__ H1buf, ull* __restrict__ qWtag,
                            float* __restrict__ Ug, float* __restrict__ Zg,
                            int* __restrict__ bar){
  const int i = blockIdx.x*blockDim.x + threadIdx.x;
  if (i < BB*HH){
    H0buf[i] = h0in[i];                // layer 0 (parity slot 0)
    H1buf[i] = h0in[BB*HH + i];        // layer 1 (parity slot 0)
    qWtag[i] = ppack(0.f, 0);          // tag 0 never matches (polls expect t+1 >= 1)
  }
  if (i < 2*BB*HH) Ug[i] = 0.0f;
  if (i < 32) Zg[i] = 0.0f;
  if (i < BAR_INTS) bar[i] = 0;
}

// Kproj = enc @ Wk^T + bk
__global__ __launch_bounds__(256, 1) void kproj_kernel(const float* __restrict__ enc,
                                                       const float* __restrict__ Wk,
                                                       const float* __restrict__ bk,
                                                       float* __restrict__ Kproj){
  __shared__ float er[BB][PITCH];
  const int bid = blockIdx.x, tid = threadIdx.x;
  const int wave = tid >> 6, lane = tid & 63;
  const int r = lane & 15, q = lane >> 4;
  const int row0 = bid*16;
  #pragma unroll
  for (int it = 0; it < 8; ++it){
    const int idx = (it*256 + tid)*4;
    const int rr = idx >> 9, h = idx & 511;
    *(float4*)&er[rr][h] = *(const float4*)&enc[(size_t)(row0+rr)*HH + h];
  }
  __syncthreads();
  float4 xr[32];
  #pragma unroll
  for (int i = 0; i < 32; ++i) xr[i] = *(const float4*)&er[r][q*128 + i*4];
  for (int k = 0; k < 128; ++k){
    const int hk = wave*128 + k;
    const float* wrow = Wk + (size_t)hk*HH + q*128;
    float acc = 0.f;
    #pragma unroll
    for (int i = 0; i < 32; ++i){
      const float4 w4 = *(const float4*)&wrow[i*4];
      acc = fmaf(w4.x,xr[i].x, fmaf(w4.y,xr[i].y, fmaf(w4.z,xr[i].z, fmaf(w4.w,xr[i].w, acc))));
    }
    acc += __shfl_xor(acc, 16);
    acc += __shfl_xor(acc, 32);
    if (lane < 16) Kproj[(size_t)(row0 + r)*HH + hk] = acc + bk[hk];
  }
}

__global__ __launch_bounds__(TPB, 1) void decoder_persist(KArgs a){
  __shared__ Smem S;
  const int bid = blockIdx.x, tid = threadIdx.x;
  const int wave = tid >> 6, lane = tid & 63;
  const int lb = lane & 15, lg = lane >> 4;
  const int j0 = bid*2;
  const int ba = bid >> 4, tb = (bid & 15) * 16;   // attention assignment
  int* bar2 = a.bar + 256;

  // ---- one-time: weights to LDS ----
  for (int g = 0; g < 4; ++g){
    for (int jj = 0; jj < 2; ++jj){
      const int row = g*HH + j0 + jj;
      for (int h = tid; h < HH; h += TPB){
        S.W0e[g][jj][h] = a.Wih0[(size_t)row*(2*HH) + h];
        S.W0c[g][jj][h] = a.Wih0[(size_t)row*(2*HH) + HH + h];
        S.W0h[g][jj][h] = a.Whh0[(size_t)row*HH + h];
        S.W1x[g][jj][h] = a.Wih1[(size_t)row*HH + h];
        S.W1h[g][jj][h] = a.Whh1[(size_t)row*HH + h];
      }
    }
  }
  for (int jj = 0; jj < 2; ++jj){
    const int d = bid*2 + jj, vo = d & 31;
    for (int h = tid; h < HH; h += TPB){
      S.Wqr[jj][h] = a.Wq[(size_t)(j0+jj)*HH + h];
      S.Wor[jj][h] = a.Wout[(size_t)vo*HH + h];
    }
  }
  for (int h = tid; h < HH; h += TPB) S.vv[h] = a.vatt[h];
  if (tid < 16){
    S.cst[0][0][tid] = a.c0in[0*BB*HH + tid*HH + j0];
    S.cst[0][1][tid] = a.c0in[0*BB*HH + tid*HH + j0 + 1];
    S.cst[1][0][tid] = a.c0in[1*BB*HH + tid*HH + j0];
    S.cst[1][1][tid] = a.c0in[1*BB*HH + tid*HH + j0 + 1];
  }
  if (tid < 8){
    const int g = tid & 3, jj = tid >> 2;
    const int row = g*HH + j0 + jj;
    S.bs0[g][jj] = a.bih0[row] + a.bhh0[row];
    S.bs1[g][jj] = a.bih1[row] + a.bhh1[row];
  }
  if (tid < 2){
    S.bqv[tid] = a.bq[j0 + tid];
    S.boutv[tid] = a.bout[(bid*2 + tid) & 31];
  }
  const float vb0 = a.vb[0];

  // ---- step-invariant attention operands -> registers ----
  float r_kp[2][8];
  #pragma unroll
  for (int i = 0; i < 2; ++i){
    const float* kp = a.Kproj + (size_t)(ba*TT + tb + wave*2 + i)*HH;
    #pragma unroll
    for (int k = 0; k < 8; ++k) r_kp[i][k] = kp[lane + 64*k];
  }
  float r_e[16];
  #pragma unroll
  for (int lt = 0; lt < 16; ++lt)
    r_e[lt] = a.enc[(size_t)(ba*TT + tb + lt)*HH + tid];
  float4 r_en[4];
  #pragma unroll
  for (int it = 0; it < 4; ++it){
    const int idx = (it*TPB + tid)*4;
    r_en[it] = *(const float4*)&a.enc[(size_t)((idx >> 9)*TT + 0)*HH + (idx & 511)];
  }
  __syncthreads();

  // ---- prologue: pre0 = bs0 + W0h @ h0_init ----
  {
    #pragma unroll
    for (int it = 0; it < 4; ++it){
      const int idx = (it*TPB + tid)*4;
      *(float4*)&S.stg[idx >> 9][idx & 511] = *(const float4*)&a.h0in[idx];
    }
    __syncthreads();
    dot8(&S.W0h[0][0][0], S.stg, S.qr.red, wave, lane);
    __syncthreads();
    if (tid < 128){
      const int jj = tid >> 6, l = tid & 63, g = l >> 4, b = l & 15;
      S.pre0[b][g][jj] = (S.qr.red[jj*4+0][l] + S.qr.red[jj*4+1][l])
                       + (S.qr.red[jj*4+2][l] + S.qr.red[jj*4+3][l]) + S.bs0[g][jj];
    }
    __syncthreads();
  }

  int e = 0;
  for (int t = 0; t < TT; ++t){
    const int par = t & 1, parn = par ^ 1;

    // ========== Phase A: h1 load+stage, logits(t-1), qW -> tagged publish ==========
    float2 r_h1[8];
    ldbuf_cc(a.H1buf + par*(BB*HH), r_h1, tid);
    stg_regs(r_h1, S.stg, tid);
    __syncthreads();   // h1 staged

    if (wave < 2){
      if (t > 0){   // logits for step t-1 from staged h1
        const int d = bid*2 + wave, bo = d >> 5, vo = d & 31;
        float acc = 0.f;
        #pragma unroll
        for (int k = 0; k < 8; ++k){
          const int h = lane + 64*k;
          acc = fmaf(S.Wor[wave][h], S.stg[bo][h], acc);
        }
        #pragma unroll
        for (int off = 32; off; off >>= 1) acc += __shfl_xor(acc, off);
        if (lane == 0) a.out[(size_t)(bo*TT + (t-1))*VV + vo] = acc + S.boutv[wave];
      }
    } else if (wave < 4){  // qW = h1 @ Wq^T + bq (2-accumulator chains)
      const int jj = wave - 2;
      const int off0 = lg * 128;
      float a0 = 0.f, a1 = 0.f;
      #pragma unroll
      for (int h = 0; h < 128; h += 8){
        const float4 w0 = *(const float4*)&S.Wqr[jj][off0 + h];
        const float4 x0 = *(const float4*)&S.stg[lb][off0 + h];
        const float4 w1 = *(const float4*)&S.Wqr[jj][off0 + h + 4];
        const float4 x1 = *(const float4*)&S.stg[lb][off0 + h + 4];
        a0 = fmaf(w0.x,x0.x, fmaf(w0.y,x0.y, fmaf(w0.z,x0.z, fmaf(w0.w,x0.w, a0))));
        a1 = fmaf(w1.x,x1.x, fmaf(w1.y,x1.y, fmaf(w1.z,x1.z, fmaf(w1.w,x1.w, a1))));
      }
      float acc = a0 + a1;
      acc += __shfl_xor(acc, 16);
      acc += __shfl_xor(acc, 32);
      if (lane < 16)
        st_pair(&a.qWtag[lane*HH + j0 + jj], acc + S.bqv[jj], t + 1);  // publish (tag t+1)
    }

    // A work fills the publish->visible gap: W1h dot + pre1; enc stage + W0e dot
    dot8(&S.W1h[0][0][0], S.stg, S.qr.red, wave, lane);   // h1 @ Whh1^T
    __syncthreads();
    if (tid < 128){
      const int jj = tid >> 6, l = tid & 63, g = l >> 4, b = l & 15;
      S.pre1[b][g][jj] = (S.qr.red[jj*4+0][l] + S.qr.red[jj*4+1][l])
                       + (S.qr.red[jj*4+2][l] + S.qr.red[jj*4+3][l]) + S.bs1[g][jj];
    }
    #pragma unroll
    for (int it = 0; it < 4; ++it){               // enc_t stage
      const int idx = (it*TPB + tid)*4;
      *(float4*)&S.stg[idx >> 9][idx & 511] = r_en[it];
    }
    __syncthreads();   // enc staged, pre1 done
    dot8(&S.W0e[0][0][0], S.stg, S.qr.red, wave, lane);   // enc_t part of Wih0
    __syncthreads();
    if (tid < 128){
      const int jj = tid >> 6, l = tid & 63, g = l >> 4, b = l & 15;
      S.pre0[b][g][jj] += (S.qr.red[jj*4+0][l] + S.qr.red[jj*4+1][l])
                        + (S.qr.red[jj*4+2][l] + S.qr.red[jj*4+3][l]);
    }
    __syncthreads();   // red reads done -> qrow (alias) safe to write

    // ========== Phase B: attention (poll tagged qW, 1 word/thread — B1 deleted) ====
    {
      float* Up = a.Ug + par*(BB*HH);
      float* Zp = a.Zg + par*16;
      {
        const ull* q = a.qWtag + ba*HH;
        int spins = 0;
        for (;;){
          const ull v = ld_pair(&q[tid]);
          if (ptag(v) == t + 1){ S.qr.qrow[tid] = pval(v); break; }
          __builtin_amdgcn_s_sleep(1);
          if (++spins > (1 << 20)) break;   // safety valve
        }
      }
      __syncthreads();
      #pragma unroll
      for (int i = 0; i < 2; ++i){
        float acc = 0.f;
        #pragma unroll
        for (int k = 0; k < 8; ++k){
          const int h = lane + 64*k;
          acc = fmaf(S.vv[h], ftanh(S.qr.qrow[h] + r_kp[i][k]), acc);
        }
        #pragma unroll
        for (int off = 32; off; off >>= 1) acc += __shfl_xor(acc, off);
        if (lane == 0) S.scw[wave*2 + i] = __expf(acc + vb0);  // |score|<=~18, exp safe
      }
      __syncthreads();
      float u = 0.f;
      #pragma unroll
      for (int lt = 0; lt < 16; ++lt)
        u = fmaf(S.scw[lt], r_e[lt], u);
      unsafeAtomicAdd(&Up[ba*HH + tid], u);
      if (tid == 0){
        float zs = 0.f;
        #pragma unroll
        for (int lt = 0; lt < 16; ++lt) zs += S.scw[lt];
        unsafeAtomicAdd(&Zp[ba], zs);
      }
    }
    gbar2(bar2, t + 1, bid, ba);   // ---- B2 per-GROUP: group ba's U,Z complete ----

    // ========== Phase C: LSTM0 (raw-U dot, post-scale by 1/Z) ==========
    {
      float2 r_u[8];
      ldbuf_cc(a.Ug + par*(BB*HH), r_u, tid);
      if (tid < 16) S.zinv[tid] = 1.0f / ldcc(&a.Zg[par*16 + tid]);
      stg_regs(r_u, S.stg, tid);
      __syncthreads();
      dot8(&S.W0c[0][0][0], S.stg, S.qr.red, wave, lane);  // raw-U part of Wih0
      __syncthreads();
      if (tid < 32){
        const int b = tid & 15, jj = tid >> 4;
        const float zi = S.zinv[b];
        float gv[4];
        #pragma unroll
        for (int g = 0; g < 4; ++g){
          const int l = g*16 + b;
          gv[g] = S.pre0[b][g][jj]
                + ((S.qr.red[jj*4+0][l] + S.qr.red[jj*4+1][l])
                 + (S.qr.red[jj*4+2][l] + S.qr.red[jj*4+3][l])) * zi;
        }
        const float cold = S.cst[0][jj][b];
        const float ii = fsig(gv[0]), ff = fsig(gv[1]);
        const float gg = ftanh(gv[2]), oo = fsig(gv[3]);
        const float cn = ff*cold + ii*gg;
        S.cst[0][jj][b] = cn;
        stcc(&a.H0buf[parn*(BB*HH) + b*HH + j0 + jj], oo * ftanh(cn));
      }
    }
    e++; gbar_arrive(a.bar, e, bid);   // ---- B3 ARRIVE (h0n stores drained) ----
    {
      // B3 window: prefetch next step's enc_t (read-only)
      const int tn = (t + 1 < TT) ? (t + 1) : t;
      #pragma unroll
      for (int it = 0; it < 4; ++it){
        const int idx = (it*TPB + tid)*4;
        r_en[it] = *(const float4*)&a.enc[(size_t)((idx >> 9)*TT + tn)*HH + (idx & 511)];
      }
    }
    gbar_wait(a.bar, e, bid);          // ---- B3 WAIT: h0n complete ----

    // ========== Phase D: LSTM1 + (B4 window) W0h dot for t+1 ==========
    {
      // zero next step's U/Z buffers (visibility rides B4; old-slot readers gated upstream)
      if (tid < 32) stcc(&a.Ug[parn*(BB*HH) + bid*32 + tid], 0.0f);
      if (bid == 0 && tid < 16) stcc(&a.Zg[parn*16 + tid], 0.0f);

      float2 r_x[8];
      ldbuf_cc(a.H0buf + parn*(BB*HH), r_x, tid);
      stg_regs(r_x, S.stg, tid);
      __syncthreads();
      dot8(&S.W1x[0][0][0], S.stg, S.qr.red, wave, lane);  // h0n @ Wih1^T
      __syncthreads();
      if (tid < 32){
        const int b = tid & 15, jj = tid >> 4;
        float gv[4];
        #pragma unroll
        for (int g = 0; g < 4; ++g){
          const int l = g*16 + b;
          gv[g] = S.pre1[b][g][jj]
                + (S.qr.red[jj*4+0][l] + S.qr.red[jj*4+1][l])
                + (S.qr.red[jj*4+2][l] + S.qr.red[jj*4+3][l]);
        }
        const float cold = S.cst[1][jj][b];
        const float ii = fsig(gv[0]), ff = fsig(gv[1]);
        const float gg = ftanh(gv[2]), oo = fsig(gv[3]);
        const float cn = ff*cold + ii*gg;
        S.cst[1][jj][b] = cn;
        stcc(&a.H1buf[parn*(BB*HH) + b*HH + j0 + jj], oo * ftanh(cn));
      }
    }
    e++; gbar_arrive(a.bar, e, bid);   // ---- B4 ARRIVE (h1n stores drained) ----
    {
      // B4 window: W0h @ h0n -> pre0 for step t+1 (stg still holds h0n; red free)
      dot8(&S.W0h[0][0][0], S.stg, S.qr.red, wave, lane);
      __syncthreads();
      if (tid < 128){
        const int jj = tid >> 6, l = tid & 63, g = l >> 4, b = l & 15;
        S.pre0[b][g][jj] = (S.qr.red[jj*4+0][l] + S.qr.red[jj*4+1][l])
                         + (S.qr.red[jj*4+2][l] + S.qr.red[jj*4+3][l]) + S.bs0[g][jj];
      }
    }
    gbar_wait(a.bar, e, bid);          // ---- B4 WAIT: h1n visible -> next step ----
  }

  // tail: logits for t=255 (final h1 is in H1buf[0] since (255+1)&1==0)
  {
    float2 r_x[8];
    ldbuf_cc(a.H1buf, r_x, tid);
    stg_regs(r_x, S.stg, tid);
    __syncthreads();
    if (wave < 2){
      const int d = bid*2 + wave, bo = d >> 5, vo = d & 31;
      float acc = 0.f;
      #pragma unroll
      for (int k = 0; k < 8; ++k){
        const int h = lane + 64*k;
        acc = fmaf(S.Wor[wave][h], S.stg[bo][h], acc);
      }
      #pragma unroll
      for (int off = 32; off; off >>= 1) acc += __shfl_xor(acc, off);
      if (lane == 0) a.out[(size_t)(bo*TT + 255)*VV + vo] = acc + S.boutv[wave];
    }
  }
}

extern "C" void kernel_launch(void* const* d_in, const int* in_sizes, int n_in,
                              void* d_out, int out_size, void* d_ws, size_t ws_size,
                              hipStream_t stream){
  const float* enc  = (const float*)d_in[0];
  const float* h0in = (const float*)d_in[1];
  const float* c0in = (const float*)d_in[2];
  // d_in[3] audio_lengths: unused by the reference
  const float* Wq   = (const float*)d_in[4];
  const float* bq   = (const float*)d_in[5];
  const float* Wk   = (const float*)d_in[6];
  const float* bk   = (const float*)d_in[7];
  const float* vatt = (const float*)d_in[8];
  const float* vb   = (const float*)d_in[9];
  const float* Wih0 = (const float*)d_in[10];
  const float* bih0 = (const float*)d_in[11];
  const float* Whh0 = (const float*)d_in[12];
  const float* bhh0 = (const float*)d_in[13];
  const float* Wih1 = (const float*)d_in[14];
  const float* bih1 = (const float*)d_in[15];
  const float* Whh1 = (const float*)d_in[16];
  const float* bhh1 = (const float*)d_in[17];
  const float* Wout = (const float*)d_in[18];
  const float* bout = (const float*)d_in[19];

  float* ws    = (float*)d_ws;
  float* Kproj = ws;                                // B*T*H = 2097152 floats
  float* H0buf = Kproj + (size_t)BB*TT*HH;          // 2*B*H (parity)
  float* H1buf = H0buf + 2*BB*HH;                   // 2*B*H (parity)
  ull*   qWtag = (ull*)(H1buf + 2*BB*HH);           // BB*HH tagged pairs (64 KB)
  float* Ug    = (float*)(qWtag + BB*HH);           // 2*B*H (parity double-buffer)
  float* Zg    = Ug + 2*BB*HH;                      // 2*16
  int*   bar   = (int*)(Zg + 32);                   // BAR_INTS ints (global + group)

  hipLaunchKernelGGL(init_kernel, dim3(64), dim3(256), 0, stream,
                     h0in, H0buf, H1buf, qWtag, Ug, Zg, bar);
  hipLaunchKernelGGL(kproj_kernel, dim3(256), dim3(256), 0, stream, enc, Wk, bk, Kproj);

  KArgs ka;
  ka.enc = enc; ka.h0in = h0in; ka.c0in = c0in;
  ka.Wq = Wq; ka.bq = bq; ka.vatt = vatt; ka.vb = vb;
  ka.Wih0 = Wih0; ka.bih0 = bih0; ka.Whh0 = Whh0; ka.bhh0 = bhh0;
  ka.Wih1 = Wih1; ka.bih1 = bih1; ka.Whh1 = Whh1; ka.bhh1 = bhh1;
  ka.Wout = Wout; ka.bout = bout;
  ka.Kproj = Kproj; ka.H0buf = H0buf; ka.H1buf = H1buf; ka.qWtag = qWtag;
  ka.Ug = Ug; ka.Zg = Zg; ka.bar = bar; ka.out = (float*)d_out;

  void* params[] = { (void*)&ka };
  hipLaunchCooperativeKernel((const void*)decoder_persist, dim3(NBLK), dim3(TPB),
                             params, 0, stream);
}

// Round 16
// 4691.750 us; speedup vs baseline: 1.2457x; 1.0166x over previous
//
#include <hip/hip_runtime.h>

#define HH 512
#define BB 16
#define TT 256
#define VV 32
#define TPB 512
#define NBLK 256
#define PITCH 516   // LDS row pitch (floats)

#define BAR_INTS 512   // 256 global slots + 256 per-group slots

struct KArgs {
  const float* enc; const float* h0in; const float* c0in;
  const float* Wq; const float* bq; const float* vatt; const float* vb;
  const float* Wih0; const float* bih0; const float* Whh0; const float* bhh0;
  const float* Wih1; const float* bih1; const float* Whh1; const float* bhh1;
  const float* Wout; const float* bout;
  const float* Kproj; float* H0buf; float* H1buf; float* qWg; float* Ug; float* Zg;
  int* bar; float* out;
};

struct Smem {
  float W0e[4][2][PITCH];   // Wih0[g*512+j][0:512]    (enc_t part)
  float W0c[4][2][PITCH];   // Wih0[g*512+j][512:1024] (ctx part)
  float W0h[4][2][PITCH];   // Whh0
  float W1x[4][2][PITCH];   // Wih1
  float W1h[4][2][PITCH];   // Whh1
  float Wqr[2][PITCH];
  float Wor[2][PITCH];
  float vv[HH];
  union { float qrow[HH]; float red[8][64]; } qr;  // time-disjoint: qrow=phase B, red=dots
  float stg[BB][PITCH];     // staging: h1 -> enc -> U -> h0n
  float pre0[BB][4][2];     // bs0 + W0h*h0_prev (B4win of t-1) + W0e*enc (B1win of t)
  float pre1[BB][4][2];     // bs1 + W1h*h1_prev (B1win of t)
  float cst[2][2][BB];      // c state [layer][jj][b]
  float scw[16];            // attention exp-weights
  float zinv[BB];
  float bs0[4][2];
  float bs1[4][2];
  float bqv[2], boutv[2];
};

__device__ __forceinline__ float fsig(float x){ return 1.0f/(1.0f + __expf(-x)); }
__device__ __forceinline__ float ftanh(float x){
  float ee = __expf(2.0f*x);
  return 1.0f - 2.0f/(ee + 1.0f);
}

// relaxed agent-scope (cross-XCD coherent, write-through, no wb/inv) — proven transport
__device__ __forceinline__ void stcc(float* p, float v){
  __hip_atomic_store(p, v, __ATOMIC_RELAXED, __HIP_MEMORY_SCOPE_AGENT);
}
__device__ __forceinline__ float ldcc(const float* p){
  return __hip_atomic_load(p, __ATOMIC_RELAXED, __HIP_MEMORY_SCOPE_AGENT);
}
__device__ __forceinline__ float2 ld2cc(const float* p){
  unsigned long long v = __hip_atomic_load((const unsigned long long*)p,
                                           __ATOMIC_RELAXED, __HIP_MEMORY_SCOPE_AGENT);
  union { unsigned long long u; float2 f; } c; c.u = v;
  return c.f;
}

// contiguous coherent load of a 16x512 buffer + LDS stage (512 threads: 8 pairs each)
__device__ __forceinline__ void ldbuf_cc(const float* __restrict__ src,
                                         float2* __restrict__ v, int tid){
  #pragma unroll
  for (int it = 0; it < 8; ++it)
    v[it] = ld2cc(&src[(it*TPB + tid)*2]);
}
__device__ __forceinline__ void stg_regs(const float2* __restrict__ v,
                                         float (* __restrict__ stg)[PITCH], int tid){
  #pragma unroll
  for (int it = 0; it < 8; ++it){
    const int i2 = (it*TPB + tid)*2;
    *(float2*)&stg[i2 >> 9][i2 & 511] = v[it];
  }
}

// ---- global split barrier (r8/r10/r12-proven): slot store + decentralized sweep ----
__device__ __forceinline__ void gbar_arrive(int* __restrict__ bar, int e, int bid){
  __syncthreads();   // per-wave vmcnt drain -> all coherent stores/atomics landed
  if (threadIdx.x == 0)
    __hip_atomic_store(&bar[bid], e, __ATOMIC_RELAXED, __HIP_MEMORY_SCOPE_AGENT);
}
__device__ __forceinline__ void gbar_wait(int* __restrict__ bar, int e, int bid){
  if (threadIdx.x < 64){
    const unsigned long long* p = (const unsigned long long*)bar;   // 128 ulls
    const int i0 = threadIdx.x * 2;
    int spins = 0;
    for (;;){
      unsigned long long v0 = __hip_atomic_load(&p[i0],     __ATOMIC_RELAXED, __HIP_MEMORY_SCOPE_AGENT);
      unsigned long long v1 = __hip_atomic_load(&p[i0 + 1], __ATOMIC_RELAXED, __HIP_MEMORY_SCOPE_AGENT);
      const int a0 = (int)v0, a1 = (int)(v0 >> 32), a2 = (int)v1, a3 = (int)(v1 >> 32);
      const int ok = (a0 >= e) & (a1 >= e) & (a2 >= e) & (a3 >= e);
      if (__all(ok)) break;
      __builtin_amdgcn_s_sleep(2);
      if (++spins > (1 << 20)) break;   // safety valve
    }
  }
  __syncthreads();
}

// ---- per-group (16-block) barrier (r12-proven) ----
__device__ __forceinline__ void gbar2(int* __restrict__ bar2, int et, int bid, int ba){
  __syncthreads();   // drains this block's U/Z atomics
  if (threadIdx.x == 0)
    __hip_atomic_store(&bar2[bid], et, __ATOMIC_RELAXED, __HIP_MEMORY_SCOPE_AGENT);
  if (threadIdx.x < 64){
    const unsigned long long* p = (const unsigned long long*)bar2 + ba*8;  // 16 ints
    int spins = 0;
    for (;;){
      int ok = 1;
      if (threadIdx.x < 8){
        unsigned long long v = __hip_atomic_load(&p[threadIdx.x], __ATOMIC_RELAXED, __HIP_MEMORY_SCOPE_AGENT);
        ok = ((int)v >= et) & ((int)(v >> 32) >= et);
      }
      if (__all(ok)) break;
      __builtin_amdgcn_s_sleep(1);
      if (++spins > (1 << 20)) break;   // safety valve
    }
  }
  __syncthreads();
}

// 8-wave dot: wave w -> (jj = w>>2, 128-h segment = w&3); lane = (g<<4)|b
// 4 independent accumulators break the FMA dependency chain (32 -> 8 deep)
__device__ __forceinline__ void dot8(const float* __restrict__ W,
                                     const float (* __restrict__ stg)[PITCH],
                                     float (* __restrict__ red)[64],
                                     int wave, int lane){
  const int jj = wave >> 2, off = (wave & 3) << 7;
  const int b = lane & 15, g = lane >> 4;
  const float* wrow = W + (size_t)(g*2 + jj)*PITCH + off;
  const float* xrow = &stg[b][off];
  float a0 = 0.f, a1 = 0.f, a2 = 0.f, a3 = 0.f;
  #pragma unroll
  for (int h = 0; h < 128; h += 16){
    const float4 w0 = *(const float4*)&wrow[h];      const float4 x0 = *(const float4*)&xrow[h];
    const float4 w1 = *(const float4*)&wrow[h + 4];  const float4 x1 = *(const float4*)&xrow[h + 4];
    const float4 w2 = *(const float4*)&wrow[h + 8];  const float4 x2 = *(const float4*)&xrow[h + 8];
    const float4 w3 = *(const float4*)&wrow[h + 12]; const float4 x3 = *(const float4*)&xrow[h + 12];
    a0 = fmaf(w0.x,x0.x, fmaf(w0.y,x0.y, fmaf(w0.z,x0.z, fmaf(w0.w,x0.w, a0))));
    a1 = fmaf(w1.x,x1.x, fmaf(w1.y,x1.y, fmaf(w1.z,x1.z, fmaf(w1.w,x1.w, a1))));
    a2 = fmaf(w2.x,x2.x, fmaf(w2.y,x2.y, fmaf(w2.z,x2.z, fmaf(w2.w,x2.w, a2))));
    a3 = fmaf(w3.x,x3.x, fmaf(w3.y,x3.y, fmaf(w3.z,x3.z, fmaf(w3.w,x3.w, a3))));
  }
  red[wave][lane] = (a0 + a1) + (a2 + a3);
}

__global__ void init_kernel(const float* __restrict__ h0in, float* __restrict__ H0buf,
                            float* __restrict__ H1buf, float* __restrict__ Ug,
                            float* __restrict__ Zg, int* __restrict__ bar){
  const int i = blockIdx.x*blockDim.x + threadIdx.x;
  if (i < BB*HH){
    H0buf[i] = h0in[i];            // layer 0
    H1buf[i] = h0in[BB*HH + i];    // layer 1
  }
  if (i < 2*BB*HH) Ug[i] = 0.0f;
  if (i < 32) Zg[i] = 0.0f;
  if (i < BAR_INTS) bar[i] = 0;
}

// Kproj = enc @ Wk^T + bk : 256 blocks x 16 (b,t)-rows, x register-cached
__global__ __launch_bounds__(256, 1) void kproj_kernel(const float* __restrict__ enc,
                                                       const float* __restrict__ Wk,
                                                       const float* __restrict__ bk,
                                                       float* __restrict__ Kproj){
  __shared__ float er[BB][PITCH];
  const int bid = blockIdx.x, tid = threadIdx.x;
  const int wave = tid >> 6, lane = tid & 63;
  const int r = lane & 15, q = lane >> 4;
  const int row0 = bid*16;
  #pragma unroll
  for (int it = 0; it < 8; ++it){
    const int idx = (it*256 + tid)*4;
    const int rr = idx >> 9, h = idx & 511;
    *(float4*)&er[rr][h] = *(const float4*)&enc[(size_t)(row0+rr)*HH + h];
  }
  __syncthreads();
  float4 xr[32];
  #pragma unroll
  for (int i = 0; i < 32; ++i) xr[i] = *(const float4*)&er[r][q*128 + i*4];
  for (int k = 0; k < 128; ++k){
    const int hk = wave*128 + k;
    const float* wrow = Wk + (size_t)hk*HH + q*128;
    float acc = 0.f;
    #pragma unroll
    for (int i = 0; i < 32; ++i){
      const float4 w4 = *(const float4*)&wrow[i*4];
      acc = fmaf(w4.x,xr[i].x, fmaf(w4.y,xr[i].y, fmaf(w4.z,xr[i].z, fmaf(w4.w,xr[i].w, acc))));
    }
    acc += __shfl_xor(acc, 16);
    acc += __shfl_xor(acc, 32);
    if (lane < 16) Kproj[(size_t)(row0 + r)*HH + hk] = acc + bk[hk];
  }
}

__global__ __launch_bounds__(TPB, 1) void decoder_persist(KArgs a){
  __shared__ Smem S;
  const int bid = blockIdx.x, tid = threadIdx.x;
  const int wave = tid >> 6, lane = tid & 63;
  const int lb = lane & 15, lg = lane >> 4;
  const int j0 = bid*2;
  const int ba = bid >> 4, tb = (bid & 15) * 16;   // attention assignment
  int* bar2 = a.bar + 256;

  // ---- one-time: weights to LDS ----
  for (int g = 0; g < 4; ++g){
    for (int jj = 0; jj < 2; ++jj){
      const int row = g*HH + j0 + jj;
      for (int h = tid; h < HH; h += TPB){
        S.W0e[g][jj][h] = a.Wih0[(size_t)row*(2*HH) + h];
        S.W0c[g][jj][h] = a.Wih0[(size_t)row*(2*HH) + HH + h];
        S.W0h[g][jj][h] = a.Whh0[(size_t)row*HH + h];
        S.W1x[g][jj][h] = a.Wih1[(size_t)row*HH + h];
        S.W1h[g][jj][h] = a.Whh1[(size_t)row*HH + h];
      }
    }
  }
  for (int jj = 0; jj < 2; ++jj){
    const int d = bid*2 + jj, vo = d & 31;
    for (int h = tid; h < HH; h += TPB){
      S.Wqr[jj][h] = a.Wq[(size_t)(j0+jj)*HH + h];
      S.Wor[jj][h] = a.Wout[(size_t)vo*HH + h];
    }
  }
  for (int h = tid; h < HH; h += TPB) S.vv[h] = a.vatt[h];
  if (tid < 16){
    S.cst[0][0][tid] = a.c0in[0*BB*HH + tid*HH + j0];
    S.cst[0][1][tid] = a.c0in[0*BB*HH + tid*HH + j0 + 1];
    S.cst[1][0][tid] = a.c0in[1*BB*HH + tid*HH + j0];
    S.cst[1][1][tid] = a.c0in[1*BB*HH + tid*HH + j0 + 1];
  }
  if (tid < 8){
    const int g = tid & 3, jj = tid >> 2;
    const int row = g*HH + j0 + jj;
    S.bs0[g][jj] = a.bih0[row] + a.bhh0[row];
    S.bs1[g][jj] = a.bih1[row] + a.bhh1[row];
  }
  if (tid < 2){
    S.bqv[tid] = a.bq[j0 + tid];
    S.boutv[tid] = a.bout[(bid*2 + tid) & 31];
  }
  const float vb0 = a.vb[0];

  // ---- step-invariant attention operands -> registers (8 waves x 2 t each) ----
  float r_kp[2][8];
  #pragma unroll
  for (int i = 0; i < 2; ++i){
    const float* kp = a.Kproj + (size_t)(ba*TT + tb + wave*2 + i)*HH;
    #pragma unroll
    for (int k = 0; k < 8; ++k) r_kp[i][k] = kp[lane + 64*k];
  }
  float r_e[16];
  #pragma unroll
  for (int lt = 0; lt < 16; ++lt)
    r_e[lt] = a.enc[(size_t)(ba*TT + tb + lt)*HH + tid];
  // enc_t prefetch for t=0 (16 floats = 4 float4 per thread)
  float4 r_en[4];
  #pragma unroll
  for (int it = 0; it < 4; ++it){
    const int idx = (it*TPB + tid)*4;
    r_en[it] = *(const float4*)&a.enc[(size_t)((idx >> 9)*TT + 0)*HH + (idx & 511)];
  }
  __syncthreads();

  // ---- prologue: pre0 = bs0 + W0h @ h0_init ----
  {
    #pragma unroll
    for (int it = 0; it < 4; ++it){
      const int idx = (it*TPB + tid)*4;
      *(float4*)&S.stg[idx >> 9][idx & 511] = *(const float4*)&a.h0in[idx];
    }
    __syncthreads();
    dot8(&S.W0h[0][0][0], S.stg, S.qr.red, wave, lane);
    __syncthreads();
    if (tid < 128){
      const int jj = tid >> 6, l = tid & 63, g = l >> 4, b = l & 15;
      S.pre0[b][g][jj] = (S.qr.red[jj*4+0][l] + S.qr.red[jj*4+1][l])
                       + (S.qr.red[jj*4+2][l] + S.qr.red[jj*4+3][l]) + S.bs0[g][jj];
    }
    __syncthreads();
  }

  int e = 0;
  for (int t = 0; t < TT; ++t){
    const int par = t & 1, parn = par ^ 1;

    // ========== Phase A: h1 load+stage, logits(t-1), qW ==========
    float2 r_h1[8];
    ldbuf_cc(a.H1buf + par*(BB*HH), r_h1, tid);
    stg_regs(r_h1, S.stg, tid);
    __syncthreads();   // h1 staged

    if (wave < 2){
      if (t > 0){   // logits for step t-1 from staged h1
        const int d = bid*2 + wave, bo = d >> 5, vo = d & 31;
        float acc = 0.f;
        #pragma unroll
        for (int k = 0; k < 8; ++k){
          const int h = lane + 64*k;
          acc = fmaf(S.Wor[wave][h], S.stg[bo][h], acc);
        }
        #pragma unroll
        for (int off = 32; off; off >>= 1) acc += __shfl_xor(acc, off);
        if (lane == 0) a.out[(size_t)(bo*TT + (t-1))*VV + vo] = acc + S.boutv[wave];
      }
    } else if (wave < 4){  // qW = h1 @ Wq^T + bq (2-accumulator chains)
      const int jj = wave - 2;
      const int off0 = lg * 128;
      float a0 = 0.f, a1 = 0.f;
      #pragma unroll
      for (int h = 0; h < 128; h += 8){
        const float4 w0 = *(const float4*)&S.Wqr[jj][off0 + h];
        const float4 x0 = *(const float4*)&S.stg[lb][off0 + h];
        const float4 w1 = *(const float4*)&S.Wqr[jj][off0 + h + 4];
        const float4 x1 = *(const float4*)&S.stg[lb][off0 + h + 4];
        a0 = fmaf(w0.x,x0.x, fmaf(w0.y,x0.y, fmaf(w0.z,x0.z, fmaf(w0.w,x0.w, a0))));
        a1 = fmaf(w1.x,x1.x, fmaf(w1.y,x1.y, fmaf(w1.z,x1.z, fmaf(w1.w,x1.w, a1))));
      }
      float acc = a0 + a1;
      acc += __shfl_xor(acc, 16);
      acc += __shfl_xor(acc, 32);
      if (lane < 16) stcc(&a.qWg[lane*HH + j0 + jj], acc + S.bqv[jj]);
    }

    e++; gbar_arrive(a.bar, e, bid);   // ---- B1 ARRIVE (qW stores drained) ----

    // B1 window: W1h dot + pre1; enc stage + W0e dot + pre0-combine
    dot8(&S.W1h[0][0][0], S.stg, S.qr.red, wave, lane);   // h1 @ Whh1^T
    __syncthreads();
    if (tid < 128){
      const int jj = tid >> 6, l = tid & 63, g = l >> 4, b = l & 15;
      S.pre1[b][g][jj] = (S.qr.red[jj*4+0][l] + S.qr.red[jj*4+1][l])
                       + (S.qr.red[jj*4+2][l] + S.qr.red[jj*4+3][l]) + S.bs1[g][jj];
    }
    #pragma unroll
    for (int it = 0; it < 4; ++it){               // enc_t stage
      const int idx = (it*TPB + tid)*4;
      *(float4*)&S.stg[idx >> 9][idx & 511] = r_en[it];
    }
    __syncthreads();   // enc staged, pre1 done
    dot8(&S.W0e[0][0][0], S.stg, S.qr.red, wave, lane);   // enc_t part of Wih0
    __syncthreads();
    if (tid < 128){
      const int jj = tid >> 6, l = tid & 63, g = l >> 4, b = l & 15;
      S.pre0[b][g][jj] += (S.qr.red[jj*4+0][l] + S.qr.red[jj*4+1][l])
                        + (S.qr.red[jj*4+2][l] + S.qr.red[jj*4+3][l]);
    }

    gbar_wait(a.bar, e, bid);   // ---- B1 WAIT: qW visible ----

    // ========== Phase B: attention ==========
    {
      float* Up = a.Ug + par*(BB*HH);
      float* Zp = a.Zg + par*16;
      const float qv = ldcc(&a.qWg[ba*HH + tid]);
      S.qr.qrow[tid] = qv;        // qrow aliases red: all red reads completed pre-B1-wait
      __syncthreads();
      #pragma unroll
      for (int i = 0; i < 2; ++i){
        float acc = 0.f;
        #pragma unroll
        for (int k = 0; k < 8; ++k){
          const int h = lane + 64*k;
          acc = fmaf(S.vv[h], ftanh(S.qr.qrow[h] + r_kp[i][k]), acc);
        }
        #pragma unroll
        for (int off = 32; off; off >>= 1) acc += __shfl_xor(acc, off);
        if (lane == 0) S.scw[wave*2 + i] = __expf(acc + vb0);  // |score| <= ~18, exp safe
      }
      __syncthreads();
      float u = 0.f;
      #pragma unroll
      for (int lt = 0; lt < 16; ++lt)
        u = fmaf(S.scw[lt], r_e[lt], u);
      unsafeAtomicAdd(&Up[ba*HH + tid], u);
      if (tid == 0){
        float zs = 0.f;
        #pragma unroll
        for (int lt = 0; lt < 16; ++lt) zs += S.scw[lt];
        unsafeAtomicAdd(&Zp[ba], zs);
      }
    }
    gbar2(bar2, t + 1, bid, ba);   // ---- B2 per-GROUP: group ba's U,Z complete ----

    // ========== Phase C: LSTM0 (raw-U dot, post-scale by 1/Z) ==========
    {
      float2 r_u[8];
      ldbuf_cc(a.Ug + par*(BB*HH), r_u, tid);
      if (tid < 16) S.zinv[tid] = 1.0f / ldcc(&a.Zg[par*16 + tid]);
      stg_regs(r_u, S.stg, tid);
      __syncthreads();
      dot8(&S.W0c[0][0][0], S.stg, S.qr.red, wave, lane);  // raw-U part of Wih0
      __syncthreads();
      if (tid < 32){
        const int b = tid & 15, jj = tid >> 4;
        const float zi = S.zinv[b];
        float gv[4];
        #pragma unroll
        for (int g = 0; g < 4; ++g){
          const int l = g*16 + b;
          gv[g] = S.pre0[b][g][jj]
                + ((S.qr.red[jj*4+0][l] + S.qr.red[jj*4+1][l])
                 + (S.qr.red[jj*4+2][l] + S.qr.red[jj*4+3][l])) * zi;
        }
        const float cold = S.cst[0][jj][b];
        const float ii = fsig(gv[0]), ff = fsig(gv[1]);
        const float gg = ftanh(gv[2]), oo = fsig(gv[3]);
        const float cn = ff*cold + ii*gg;
        S.cst[0][jj][b] = cn;
        stcc(&a.H0buf[parn*(BB*HH) + b*HH + j0 + jj], oo * ftanh(cn));
      }
    }
    e++; gbar_arrive(a.bar, e, bid);   // ---- B3 ARRIVE (h0n stores drained) ----
    {
      // B3 window: prefetch next step's enc_t (read-only)
      const int tn = (t + 1 < TT) ? (t + 1) : t;
      #pragma unroll
      for (int it = 0; it < 4; ++it){
        const int idx = (it*TPB + tid)*4;
        r_en[it] = *(const float4*)&a.enc[(size_t)((idx >> 9)*TT + tn)*HH + (idx & 511)];
      }
    }
    gbar_wait(a.bar, e, bid);          // ---- B3 WAIT: h0n complete ----

    // ========== Phase D: LSTM1 + (B4 window) W0h dot for t+1 ==========
    {
      // zero next step's U/Z buffers (visibility rides B4; old-slot readers gated by B1)
      if (tid < 32) stcc(&a.Ug[parn*(BB*HH) + bid*32 + tid], 0.0f);
      if (bid == 0 && tid < 16) stcc(&a.Zg[parn*16 + tid], 0.0f);

      float2 r_x[8];
      ldbuf_cc(a.H0buf + parn*(BB*HH), r_x, tid);
      stg_regs(r_x, S.stg, tid);
      __syncthreads();
      dot8(&S.W1x[0][0][0], S.stg, S.qr.red, wave, lane);  // h0n @ Wih1^T
      __syncthreads();
      if (tid < 32){
        const int b = tid & 15, jj = tid >> 4;
        float gv[4];
        #pragma unroll
        for (int g = 0; g < 4; ++g){
          const int l = g*16 + b;
          gv[g] = S.pre1[b][g][jj]
                + (S.qr.red[jj*4+0][l] + S.qr.red[jj*4+1][l])
                + (S.qr.red[jj*4+2][l] + S.qr.red[jj*4+3][l]);
        }
        const float cold = S.cst[1][jj][b];
        const float ii = fsig(gv[0]), ff = fsig(gv[1]);
        const float gg = ftanh(gv[2]), oo = fsig(gv[3]);
        const float cn = ff*cold + ii*gg;
        S.cst[1][jj][b] = cn;
        stcc(&a.H1buf[parn*(BB*HH) + b*HH + j0 + jj], oo * ftanh(cn));
      }
    }
    e++; gbar_arrive(a.bar, e, bid);   // ---- B4 ARRIVE (h1n stores drained) ----
    {
      // B4 window: W0h @ h0n -> pre0 for step t+1 (stg still holds h0n; red free)
      dot8(&S.W0h[0][0][0], S.stg, S.qr.red, wave, lane);
      __syncthreads();
      if (tid < 128){
        const int jj = tid >> 6, l = tid & 63, g = l >> 4, b = l & 15;
        S.pre0[b][g][jj] = (S.qr.red[jj*4+0][l] + S.qr.red[jj*4+1][l])
                         + (S.qr.red[jj*4+2][l] + S.qr.red[jj*4+3][l]) + S.bs0[g][jj];
      }
    }
    gbar_wait(a.bar, e, bid);          // ---- B4 WAIT: h1n complete -> next step ----
  }

  // tail: logits for t=255 (final h1 is in H1buf[0] since (255+1)&1==0)
  {
    float2 r_x[8];
    ldbuf_cc(a.H1buf, r_x, tid);
    stg_regs(r_x, S.stg, tid);
    __syncthreads();
    if (wave < 2){
      const int d = bid*2 + wave, bo = d >> 5, vo = d & 31;
      float acc = 0.f;
      #pragma unroll
      for (int k = 0; k < 8; ++k){
        const int h = lane + 64*k;
        acc = fmaf(S.Wor[wave][h], S.stg[bo][h], acc);
      }
      #pragma unroll
      for (int off = 32; off; off >>= 1) acc += __shfl_xor(acc, off);
      if (lane == 0) a.out[(size_t)(bo*TT + 255)*VV + vo] = acc + S.boutv[wave];
    }
  }
}

extern "C" void kernel_launch(void* const* d_in, const int* in_sizes, int n_in,
                              void* d_out, int out_size, void* d_ws, size_t ws_size,
                              hipStream_t stream){
  const float* enc  = (const float*)d_in[0];
  const float* h0in = (const float*)d_in[1];
  const float* c0in = (const float*)d_in[2];
  // d_in[3] audio_lengths: unused by the reference
  const float* Wq   = (const float*)d_in[4];
  const float* bq   = (const float*)d_in[5];
  const float* Wk   = (const float*)d_in[6];
  const float* bk   = (const float*)d_in[7];
  const float* vatt = (const float*)d_in[8];
  const float* vb   = (const float*)d_in[9];
  const float* Wih0 = (const float*)d_in[10];
  const float* bih0 = (const float*)d_in[11];
  const float* Whh0 = (const float*)d_in[12];
  const float* bhh0 = (const float*)d_in[13];
  const float* Wih1 = (const float*)d_in[14];
  const float* bih1 = (const float*)d_in[15];
  const float* Whh1 = (const float*)d_in[16];
  const float* bhh1 = (const float*)d_in[17];
  const float* Wout = (const float*)d_in[18];
  const float* bout = (const float*)d_in[19];

  float* ws    = (float*)d_ws;
  float* Kproj = ws;                               // B*T*H = 2097152
  float* H0buf = Kproj + (size_t)BB*TT*HH;         // 2*B*H
  float* H1buf = H0buf + 2*BB*HH;                  // 2*B*H
  float* qWg   = H1buf + 2*BB*HH;                  // B*H
  float* Ug    = qWg + BB*HH;                      // 2*B*H (parity double-buffer)
  float* Zg    = Ug + 2*BB*HH;                     // 2*16
  int*   bar   = (int*)(Zg + 32);                  // BAR_INTS ints (global + group)

  hipLaunchKernelGGL(init_kernel, dim3(64), dim3(256), 0, stream,
                     h0in, H0buf, H1buf, Ug, Zg, bar);
  hipLaunchKernelGGL(kproj_kernel, dim3(256), dim3(256), 0, stream, enc, Wk, bk, Kproj);

  KArgs ka;
  ka.enc = enc; ka.h0in = h0in; ka.c0in = c0in;
  ka.Wq = Wq; ka.bq = bq; ka.vatt = vatt; ka.vb = vb;
  ka.Wih0 = Wih0; ka.bih0 = bih0; ka.Whh0 = Whh0; ka.bhh0 = bhh0;
  ka.Wih1 = Wih1; ka.bih1 = bih1; ka.Whh1 = Whh1; ka.bhh1 = bhh1;
  ka.Wout = Wout; ka.bout = bout;
  ka.Kproj = Kproj; ka.H0buf = H0buf; ka.H1buf = H1buf;
  ka.qWg = qWg; ka.Ug = Ug; ka.Zg = Zg; ka.bar = bar; ka.out = (float*)d_out;

  void* params[] = { (void*)&ka };
  hipLaunchCooperativeKernel((const void*)decoder_persist, dim3(NBLK), dim3(TPB),
                             params, 0, stream);
}